// Round 14
// baseline (4260.735 us; speedup 1.0000x reference)
//
#include <hip/hip_runtime.h>

#define L 6
#define D 1024
#define DFF 4096
#define BATCH 4
#define S 1024

typedef __attribute__((ext_vector_type(4))) float f32x4;
typedef __attribute__((ext_vector_type(16))) float f32x16;
typedef __attribute__((ext_vector_type(8))) short short8;

__device__ __forceinline__ ushort f2bf(float f) {
    unsigned int u = __float_as_uint(f);
    u = u + 0x7FFF + ((u >> 16) & 1);
    return (ushort)(u >> 16);
}
__device__ __forceinline__ float bf2f(ushort u) {
    return __uint_as_float(((unsigned int)u) << 16);
}
__device__ __forceinline__ void gload16(const ushort* g, ushort* l) {
    __builtin_amdgcn_global_load_lds(
        (const __attribute__((address_space(1))) void*)g,
        (__attribute__((address_space(3))) void*)l, 16, 0, 0);
}

// ---------------- split f32 -> (hi, lo) bf16 planes ----------------
__global__ __launch_bounds__(256) void cvt_split(const float* __restrict__ in,
                                                 ushort* __restrict__ oh,
                                                 ushort* __restrict__ ol, int n) {
    int i = (blockIdx.x * 256 + threadIdx.x) * 4;
    if (i >= n) return;
    float4 v = *(const float4*)&in[i];
    ushort4 h, l;
    h.x = f2bf(v.x); l.x = f2bf(v.x - bf2f(h.x));
    h.y = f2bf(v.y); l.y = f2bf(v.y - bf2f(h.y));
    h.z = f2bf(v.z); l.z = f2bf(v.z - bf2f(h.z));
    h.w = f2bf(v.w); l.w = f2bf(v.w - bf2f(h.w));
    *(ushort4*)&oh[i] = h;
    *(ushort4*)&ol[i] = l;
}

// ------- transpose up to 3 weights [K,N] f32 -> stacked [z*N + n][K] h/l bf16 -------
__global__ __launch_bounds__(256) void transpose_w(const float* __restrict__ W0,
                                                   const float* __restrict__ W1,
                                                   const float* __restrict__ W2,
                                                   ushort* __restrict__ outh,
                                                   ushort* __restrict__ outl,
                                                   int K, int N) {
    const float* W = blockIdx.z == 0 ? W0 : (blockIdx.z == 1 ? W1 : W2);
    __shared__ float T[32][33];
    int n0 = blockIdx.x * 32, k0 = blockIdx.y * 32;
    int t = threadIdx.x;
    int r = t >> 3, c4 = (t & 7) * 4;
    float4 v = *(const float4*)&W[(size_t)(k0 + r) * N + n0 + c4];
    T[r][c4 + 0] = v.x; T[r][c4 + 1] = v.y; T[r][c4 + 2] = v.z; T[r][c4 + 3] = v.w;
    __syncthreads();
    float a0 = T[c4 + 0][r], a1 = T[c4 + 1][r], a2 = T[c4 + 2][r], a3 = T[c4 + 3][r];
    ushort4 h, l;
    h.x = f2bf(a0); l.x = f2bf(a0 - bf2f(h.x));
    h.y = f2bf(a1); l.y = f2bf(a1 - bf2f(h.y));
    h.z = f2bf(a2); l.z = f2bf(a2 - bf2f(h.z));
    h.w = f2bf(a3); l.w = f2bf(a3 - bf2f(h.w));
    size_t ob = ((size_t)blockIdx.z * N + n0 + r) * K + k0 + c4;
    *(ushort4*)&outh[ob] = h;
    *(ushort4*)&outl[ob] = l;
}

// ---------------- transpose V planes [b][s][3072-strided] -> [b][d][s] ----------------
__global__ __launch_bounds__(256) void vtrans(const ushort* __restrict__ inh,
                                              const ushort* __restrict__ inl,
                                              ushort* __restrict__ outh,
                                              ushort* __restrict__ outl,
                                              int ld_in, int col_off) {
    __shared__ ushort T[32][40];
    const int pz = blockIdx.z, b = pz >> 1;
    const ushort* in = (pz & 1) ? inl : inh;
    ushort* out = (pz & 1) ? outl : outh;
    const int d0 = blockIdx.x * 32, s0 = blockIdx.y * 32;
    const int t = threadIdx.x, r = t >> 3, c4 = (t & 7) * 4;
    ushort4 v = *(const ushort4*)&in[(size_t)(b * S + s0 + r) * ld_in + col_off + d0 + c4];
    T[r][c4 + 0] = v.x; T[r][c4 + 1] = v.y; T[r][c4 + 2] = v.z; T[r][c4 + 3] = v.w;
    __syncthreads();
    ushort4 o = {T[c4 + 0][r], T[c4 + 1][r], T[c4 + 2][r], T[c4 + 3][r]};
    *(ushort4*)&out[(size_t)(b * D + d0 + r) * S + s0 + c4] = o;
}

// ============ gemm8: 256x256 deep-prefetch split-precision GEMM (big-N, z=1) ============
// All 24 fragment ds_reads issued at K-tile top (program order = cluster order);
// compiler inserts counted lgkmcnt so reads overlap MFMA. vmcnt(8) counted at top.
#define MFMA32(d, a, b) d = __builtin_amdgcn_mfma_f32_32x32x16_bf16(a, b, d, 0, 0, 0)
#define CLUSTER12(MB, A0H, A0L, A1H, A1L, B0H, B0L, B1H, B1L)                          \
    MFMA32(acc[MB][0], A0H, B0H); MFMA32(acc[MB][0], A0H, B0L);                        \
    MFMA32(acc[MB][0], A0L, B0H);                                                      \
    MFMA32(acc[MB][1], A0H, B1H); MFMA32(acc[MB][1], A0H, B1L);                        \
    MFMA32(acc[MB][1], A0L, B1H);                                                      \
    MFMA32(acc[MB + 1][0], A1H, B0H); MFMA32(acc[MB + 1][0], A1H, B0L);                \
    MFMA32(acc[MB + 1][0], A1L, B0H);                                                  \
    MFMA32(acc[MB + 1][1], A1H, B1H); MFMA32(acc[MB + 1][1], A1H, B1L);                \
    MFMA32(acc[MB + 1][1], A1L, B1H);

__global__ __launch_bounds__(512, 2) void gemm8(
    const ushort* __restrict__ Ah, const ushort* __restrict__ Al,
    const ushort* __restrict__ Bh, const ushort* __restrict__ Bl,
    ushort* __restrict__ Ch, ushort* __restrict__ Cl,
    const float* __restrict__ bias, float alpha,
    int M, int N, int K, int lda, int ldb, int ldc) {
    __shared__ ushort lds[65536];   // 128 KiB: [buf2][plane4][row256][col32]

    const int gx = gridDim.x, gy = gridDim.y;
    int nblk = gx * gy;
    int bid = blockIdx.y * gx + blockIdx.x;
    if ((nblk & 7) == 0) bid = (bid & 7) * (nblk >> 3) + (bid >> 3);
    const int bx = bid % gx, by = bid / gx;
    const int bm = by * 256, bn = bx * 256;

    const int tid = threadIdx.x, lane = tid & 63, w = tid >> 6;
    const int wr = w >> 2, wc = w & 3;        // 2 x 4 wave grid
    const int l31 = lane & 31, hi = lane >> 5;

    f32x16 acc[4][2] = {};
    const int NT = K >> 5;

    auto stage_tile = [&](int kt) {
        const int bufo = (kt & 1) * 32768;
#pragma unroll
        for (int h = 0; h < 2; h++) {
            const int row = h * 128 + (w << 4) + (lane >> 2);
            const int ps = lane & 3;
            const int col = (kt << 5) + ((ps ^ ((row >> 1) & 3)) << 3);  // pre-swizzled src
            const int drow = h * 128 + (w << 4);
            gload16(Ah + (size_t)(bm + row) * lda + col, lds + bufo + 0 * 8192 + drow * 32);
            gload16(Al + (size_t)(bm + row) * lda + col, lds + bufo + 1 * 8192 + drow * 32);
            gload16(Bh + (size_t)(bn + row) * ldb + col, lds + bufo + 2 * 8192 + drow * 32);
            gload16(Bl + (size_t)(bn + row) * ldb + col, lds + bufo + 3 * 8192 + drow * 32);
        }
    };
    auto rdA = [&](int bufo, int mi, int pl, int ksub) -> short8 {
        const int row = wr * 128 + mi * 32 + l31;
        const int ps = (ksub * 2 + hi) ^ ((row >> 1) & 3);
        return *(const short8*)&lds[bufo + pl * 8192 + row * 32 + ps * 8];
    };
    auto rdB = [&](int bufo, int nj, int pl, int ksub) -> short8 {
        const int row = wc * 64 + nj * 32 + l31;
        const int ps = (ksub * 2 + hi) ^ ((row >> 1) & 3);
        return *(const short8*)&lds[bufo + (2 + pl) * 8192 + row * 32 + ps * 8];
    };

    stage_tile(0);
    if (NT > 1) stage_tile(1);

    for (int kt = 0; kt < NT; kt++) {
        const int bufo = (kt & 1) * 32768;
        if (kt + 1 < NT) {
            asm volatile("s_waitcnt vmcnt(8)" ::: "memory");   // tile kt fully landed
        } else {
            asm volatile("s_waitcnt vmcnt(0)" ::: "memory");
        }
        __builtin_amdgcn_s_barrier();       // collective: everyone's loads for kt done
        __builtin_amdgcn_sched_barrier(0);
        // ---- issue ALL fragment reads up front (cluster order); compiler emits
        // counted lgkmcnt so later clusters' reads overlap earlier clusters' MFMA ----
        short8 b00h = rdB(bufo, 0, 0, 0), b00l = rdB(bufo, 0, 1, 0);
        short8 b10h = rdB(bufo, 1, 0, 0), b10l = rdB(bufo, 1, 1, 0);
        short8 a00h = rdA(bufo, 0, 0, 0), a00l = rdA(bufo, 0, 1, 0);
        short8 a10h = rdA(bufo, 1, 0, 0), a10l = rdA(bufo, 1, 1, 0);
        short8 a20h = rdA(bufo, 2, 0, 0), a20l = rdA(bufo, 2, 1, 0);
        short8 a30h = rdA(bufo, 3, 0, 0), a30l = rdA(bufo, 3, 1, 0);
        short8 b01h = rdB(bufo, 0, 0, 1), b01l = rdB(bufo, 0, 1, 1);
        short8 b11h = rdB(bufo, 1, 0, 1), b11l = rdB(bufo, 1, 1, 1);
        short8 a01h = rdA(bufo, 0, 0, 1), a01l = rdA(bufo, 0, 1, 1);
        short8 a11h = rdA(bufo, 1, 0, 1), a11l = rdA(bufo, 1, 1, 1);
        short8 a21h = rdA(bufo, 2, 0, 1), a21l = rdA(bufo, 2, 1, 1);
        short8 a31h = rdA(bufo, 3, 0, 1), a31l = rdA(bufo, 3, 1, 1);
        __builtin_amdgcn_s_setprio(1);
        CLUSTER12(0, a00h, a00l, a10h, a10l, b00h, b00l, b10h, b10l);
        CLUSTER12(2, a20h, a20l, a30h, a30l, b00h, b00l, b10h, b10l);
        CLUSTER12(0, a01h, a01l, a11h, a11l, b01h, b01l, b11h, b11l);
        __builtin_amdgcn_s_setprio(0);
        asm volatile("s_waitcnt lgkmcnt(0)" ::: "memory");  // all reads of buf done
        __builtin_amdgcn_sched_barrier(0);
        __builtin_amdgcn_s_barrier();       // all waves done reading buf[kt&1]
        if (kt + 2 < NT) stage_tile(kt + 2);  // overwrite under final MFMA cluster
        __builtin_amdgcn_s_setprio(1);
        CLUSTER12(2, a21h, a21l, a31h, a31l, b01h, b01l, b11h, b11l);
        __builtin_amdgcn_s_setprio(0);
    }

#pragma unroll
    for (int mi = 0; mi < 4; mi++) {
#pragma unroll
        for (int nj = 0; nj < 2; nj++) {
            const int n = bn + wc * 64 + nj * 32 + l31;
            const float bv = bias ? bias[n] : 0.f;
#pragma unroll
            for (int r = 0; r < 16; r++) {
                const int m = bm + wr * 128 + mi * 32 + (r & 3) + 8 * (r >> 2) + 4 * hi;
                float v = acc[mi][nj][r] * alpha + bv;
                const size_t ci = (size_t)m * ldc + n;
                ushort h = f2bf(v);
                Ch[ci] = h;
                Cl[ci] = f2bf(v - bf2f(h));
            }
        }
    }
}

// ---------------- gemm3: 128x128 split-precision GEMM (round-8 proven) ----------------
// triMode: 0 none; 1 = causal scores (skip bx>by); 2 = causal PV (cap K-tiles at 2*by+2)
__global__ __launch_bounds__(256) void gemm3(
    const ushort* __restrict__ Ah, const ushort* __restrict__ Al,
    const ushort* __restrict__ Bh, const ushort* __restrict__ Bl,
    float* __restrict__ Cf, ushort* __restrict__ Ch, ushort* __restrict__ Cl,
    const float* __restrict__ bias, float alpha,
    int M, int N, int K, int lda, int ldb, int ldc,
    long sA, long sB, long sC, int triMode) {
    __shared__ ushort lds[4 * 128 * 64];
    ushort* Ash = lds;
    ushort* Asl = lds + 128 * 64;
    ushort* Bsh = lds + 2 * 128 * 64;
    ushort* Bsl = lds + 3 * 128 * 64;

    const int gx = gridDim.x, gy = gridDim.y;
    int nblk = gx * gy * gridDim.z;
    int bid = (blockIdx.z * gy + blockIdx.y) * gx + blockIdx.x;
    if ((nblk & 7) == 0) bid = (bid & 7) * (nblk >> 3) + (bid >> 3);
    const int bx = bid % gx;
    int rem = bid / gx;
    const int by = rem % gy;
    const int z = rem / gy;

    if (triMode == 1 && bx > by) return;      // fully-masked causal score block
    int NT = K >> 6;
    if (triMode == 2) {                        // P rows are zero beyond diagonal
        int cap = 2 * by + 2;
        if (cap < NT) NT = cap;
    }

    const int bm = by * 128, bn = bx * 128;
    const ushort* A0 = Ah + (size_t)z * sA;
    const ushort* A1 = Al + (size_t)z * sA;
    const ushort* B0 = Bh + (size_t)z * sB;
    const ushort* B1 = Bl + (size_t)z * sB;
    const size_t coff = (size_t)z * sC;

    const int tid = threadIdx.x, lane = tid & 63;
    const int wid = tid >> 6, wr = wid >> 1, wc = wid & 1;
    const int lr = lane & 15, lg = lane >> 4;

    f32x4 acc[4][4] = {};

    for (int kt = 0; kt < NT; kt++) {
        const int k0 = kt << 6;
        if (kt) __syncthreads();
#pragma unroll
        for (int c = 0; c < 4; c++) {
            const int idx = c * 256 + tid;
            const int row = idx >> 3;
            const int col = (((idx & 7) ^ (row & 7)) * 8);
            const int lbase = (c * 256 + (tid & 192)) * 8;
            const size_t aoff = (size_t)(bm + row) * lda + k0 + col;
            const size_t boff = (size_t)(bn + row) * ldb + k0 + col;
            gload16(A0 + aoff, Ash + lbase);
            gload16(A1 + aoff, Asl + lbase);
            gload16(B0 + boff, Bsh + lbase);
            gload16(B1 + boff, Bsl + lbase);
        }
        asm volatile("s_waitcnt vmcnt(0)" ::: "memory");
        __syncthreads();
#pragma unroll
        for (int ks = 0; ks < 2; ks++) {
            short8 afh[4], afl[4], bfh[4], bfl[4];
#pragma unroll
            for (int i = 0; i < 4; i++) {
                const int arow = wr * 64 + i * 16 + lr;
                const int brow = wc * 64 + i * 16 + lr;
                const int ar = arow * 64 + ((ks * 4 + lg) ^ (arow & 7)) * 8;
                const int br = brow * 64 + ((ks * 4 + lg) ^ (brow & 7)) * 8;
                afh[i] = *(const short8*)&Ash[ar];
                afl[i] = *(const short8*)&Asl[ar];
                bfh[i] = *(const short8*)&Bsh[br];
                bfl[i] = *(const short8*)&Bsl[br];
            }
#pragma unroll
            for (int i = 0; i < 4; i++)
#pragma unroll
                for (int j = 0; j < 4; j++) {
                    acc[i][j] = __builtin_amdgcn_mfma_f32_16x16x32_bf16(afh[i], bfh[j], acc[i][j], 0, 0, 0);
                    acc[i][j] = __builtin_amdgcn_mfma_f32_16x16x32_bf16(afh[i], bfl[j], acc[i][j], 0, 0, 0);
                    acc[i][j] = __builtin_amdgcn_mfma_f32_16x16x32_bf16(afl[i], bfh[j], acc[i][j], 0, 0, 0);
                }
        }
    }
#pragma unroll
    for (int j = 0; j < 4; j++) {
        const int n = bn + wc * 64 + j * 16 + lr;
        const float bv = bias ? bias[n] : 0.f;
#pragma unroll
        for (int i = 0; i < 4; i++) {
#pragma unroll
            for (int r = 0; r < 4; r++) {
                const int m = bm + wr * 64 + i * 16 + lg * 4 + r;
                float v = acc[i][j][r] * alpha + bv;
                const size_t ci = coff + (size_t)m * ldc + n;
                if (Cf) Cf[ci] = v;
                if (Ch) {
                    ushort h = f2bf(v);
                    Ch[ci] = h;
                    Cl[ci] = f2bf(v - bf2f(h));
                }
            }
        }
    }
}

// ---------------- row softmax (f32 in, h/l bf16 planes out) ----------------
__global__ __launch_bounds__(256) void softmax_rows(const float* __restrict__ Sc,
                                                    ushort* __restrict__ Ph,
                                                    ushort* __restrict__ Pl, int causal) {
    __shared__ float red[4];
    int q = blockIdx.x, b = blockIdx.y;
    size_t base = ((size_t)b * S + q) * S;
    int valid = causal ? (q + 1) : S;
    int tid = threadIdx.x;
    float v[4];
    float mx = -3e38f;
#pragma unroll
    for (int j = 0; j < 4; j++) {
        int c = tid + j * 256;
        float x = (c < valid) ? Sc[base + c] : -3e38f;
        v[j] = x;
        mx = fmaxf(mx, v[j]);
    }
    for (int o = 32; o; o >>= 1) mx = fmaxf(mx, __shfl_xor(mx, o));
    if ((tid & 63) == 0) red[tid >> 6] = mx;
    __syncthreads();
    mx = fmaxf(fmaxf(red[0], red[1]), fmaxf(red[2], red[3]));
    float s = 0.f;
#pragma unroll
    for (int j = 0; j < 4; j++) {
        int c = tid + j * 256;
        float e = (c < valid) ? __expf(v[j] - mx) : 0.f;
        v[j] = e;
        s += e;
    }
    for (int o = 32; o; o >>= 1) s += __shfl_xor(s, o);
    __syncthreads();
    if ((tid & 63) == 0) red[tid >> 6] = s;
    __syncthreads();
    s = red[0] + red[1] + red[2] + red[3];
    float inv = 1.0f / s;
#pragma unroll
    for (int j = 0; j < 4; j++) {
        int c = tid + j * 256;
        float p = v[j] * inv;
        ushort h = f2bf(p);
        Ph[base + c] = h;
        Pl[base + c] = f2bf(p - bf2f(h));
    }
}

// ---------------- residual + layernorm (f32 in, f32 + h/l planes out) ----------------
__global__ __launch_bounds__(256) void ln_res(const float* __restrict__ xin,
                                              const float* __restrict__ y,
                                              const float* __restrict__ g,
                                              const float* __restrict__ bta,
                                              float* __restrict__ xof,
                                              ushort* __restrict__ xh,
                                              ushort* __restrict__ xl) {
    __shared__ float red[4];
    int row = blockIdx.x;
    size_t base = (size_t)row * D;
    int tid = threadIdx.x;
    int c0 = tid * 4;
    float4 xv = *(const float4*)&xin[base + c0];
    float4 yv = *(const float4*)&y[base + c0];
    float t[4] = {xv.x + yv.x, xv.y + yv.y, xv.z + yv.z, xv.w + yv.w};
    float s = t[0] + t[1] + t[2] + t[3];
    for (int o = 32; o; o >>= 1) s += __shfl_xor(s, o);
    if ((tid & 63) == 0) red[tid >> 6] = s;
    __syncthreads();
    s = red[0] + red[1] + red[2] + red[3];
    float mean = s * (1.0f / D);
    float vs = 0.f;
#pragma unroll
    for (int j = 0; j < 4; j++) {
        float dd = t[j] - mean;
        vs += dd * dd;
    }
    for (int o = 32; o; o >>= 1) vs += __shfl_xor(vs, o);
    __syncthreads();
    if ((tid & 63) == 0) red[tid >> 6] = vs;
    __syncthreads();
    vs = red[0] + red[1] + red[2] + red[3];
    float inv = rsqrtf(vs * (1.0f / D) + 1e-5f);
    float4 gv = *(const float4*)&g[c0];
    float4 bv = *(const float4*)&bta[c0];
    float o0 = (t[0] - mean) * inv * gv.x + bv.x;
    float o1 = (t[1] - mean) * inv * gv.y + bv.y;
    float o2 = (t[2] - mean) * inv * gv.z + bv.z;
    float o3 = (t[3] - mean) * inv * gv.w + bv.w;
    float4 fo = {o0, o1, o2, o3};
    *(float4*)&xof[base + c0] = fo;
    ushort4 h, l;
    h.x = f2bf(o0); l.x = f2bf(o0 - bf2f(h.x));
    h.y = f2bf(o1); l.y = f2bf(o1 - bf2f(h.y));
    h.z = f2bf(o2); l.z = f2bf(o2 - bf2f(h.z));
    h.w = f2bf(o3); l.w = f2bf(o3 - bf2f(h.w));
    *(ushort4*)&xh[base + c0] = h;
    *(ushort4*)&xl[base + c0] = l;
}

__global__ __launch_bounds__(256) void fill_f32(float* out, float v, int n) {
    int i = (blockIdx.x * 256 + threadIdx.x) * 4;
    if (i >= n) return;
    float4 f = {v, v, v, v};
    *(float4*)&out[i] = f;
}

extern "C" void kernel_launch(void* const* d_in, const int* in_sizes, int n_in,
                              void* d_out, int out_size, void* d_ws, size_t ws_size,
                              hipStream_t stream) {
    dim3 blk(256);
    const int M = BATCH * S;  // 4096
    const int fill_blocks = (out_size / 4 + 255) / 256;

    int base = n_in - 18;
    bool layout_ok = (base >= 2) && (out_size == M * D) &&
                     (in_sizes[0] == M * D) && (in_sizes[1] == M * D) &&
                     (in_sizes[base] == L * D * D) && (in_sizes[base + 4] == L * D) &&
                     (in_sizes[base + 12] == L * D * DFF) && (in_sizes[base + 13] == L * DFF);
    if (!layout_ok) {
        fill_f32<<<fill_blocks, blk, 0, stream>>>((float*)d_out, 9000.f, out_size);
        return;
    }
    const float* x_in = (const float*)d_in[0];
    const float* enc  = (const float*)d_in[1];
    const float* Wq1 = (const float*)d_in[base + 0];
    const float* Wk1 = (const float*)d_in[base + 1];
    const float* Wv1 = (const float*)d_in[base + 2];
    const float* Wo1 = (const float*)d_in[base + 3];
    const float* g1  = (const float*)d_in[base + 4];
    const float* b1  = (const float*)d_in[base + 5];
    const float* Wq2 = (const float*)d_in[base + 6];
    const float* Wk2 = (const float*)d_in[base + 7];
    const float* Wv2 = (const float*)d_in[base + 8];
    const float* Wo2 = (const float*)d_in[base + 9];
    const float* g2  = (const float*)d_in[base + 10];
    const float* b2  = (const float*)d_in[base + 11];
    const float* Wf1 = (const float*)d_in[base + 12];
    const float* bf1 = (const float*)d_in[base + 13];
    const float* Wf2 = (const float*)d_in[base + 14];
    const float* bf2 = (const float*)d_in[base + 15];
    const float* g3  = (const float*)d_in[base + 16];
    const float* b3  = (const float*)d_in[base + 17];

    const size_t PL = (size_t)M * D * 2;   // 8 MiB bf16 plane
    const size_t required = 22 * PL;       // 176 MiB
    if (ws_size < required) {
        fill_f32<<<fill_blocks, blk, 0, stream>>>((float*)d_out, 500.f, out_size);
        return;
    }

    char* ws = (char*)d_ws;
    size_t off = 0;
    auto carve = [&](size_t bytes) -> char* {
        char* p = ws + off;
        off += (bytes + 255) & ~(size_t)255;
        return p;
    };
    float*  xf = (float*)carve(2 * PL);
    ushort* xh = (ushort*)carve(PL);
    ushort* xl = (ushort*)carve(PL);
    ushort* eh = (ushort*)carve(PL);
    ushort* el = (ushort*)carve(PL);
    char*   clu = carve(10 * PL);
    ushort* qkvh = (ushort*)clu;                 // 3 PL (4096 x 3072)
    ushort* qkvl = (ushort*)(clu + 3 * PL);      // 3 PL
    ushort* vth  = (ushort*)(clu + 6 * PL);      // [b][d][s]
    ushort* vtl  = (ushort*)(clu + 7 * PL);
    float*  scores = (float*)(clu + 8 * PL);     // 2 PL f32, aliases at-planes
    ushort* ath  = (ushort*)(clu + 8 * PL);
    ushort* atl  = (ushort*)(clu + 9 * PL);
    ushort* hph  = (ushort*)clu;                 // FFN hidden aliases qkv+vt (4 PL each)
    ushort* hpl  = (ushort*)(clu + 4 * PL);
    ushort* ph = (ushort*)carve(PL);
    ushort* pl_ = (ushort*)carve(PL);
    float*  yf = (float*)carve(2 * PL);
    ushort* wth = (ushort*)carve(PL);
    ushort* wtl = (ushort*)carve(PL);

    auto gemm = [&](const ushort* Ah, const ushort* Al, const ushort* Bh, const ushort* Bl,
                    float* Cf, ushort* Ch, ushort* Cl, const float* bias, float alpha,
                    int gm, int gn, int gk, int lda, int ldb, int ldc,
                    long sA, long sB, long sC, int batch, int tri) {
        dim3 g(gn / 128, gm / 128, batch);
        gemm3<<<g, blk, 0, stream>>>(Ah, Al, Bh, Bl, Cf, Ch, Cl, bias, alpha,
                                     gm, gn, gk, lda, ldb, ldc, sA, sB, sC, tri);
    };
    auto gemmBig = [&](const ushort* Ah, const ushort* Al, const ushort* Bh, const ushort* Bl,
                       ushort* Ch, ushort* Cl, const float* bias,
                       int gm, int gn, int gk, int lda, int ldb, int ldc) {
        dim3 g(gn / 256, gm / 256);
        gemm8<<<g, dim3(512), 0, stream>>>(Ah, Al, Bh, Bl, Ch, Cl, bias, 1.f,
                                           gm, gn, gk, lda, ldb, ldc);
    };
    auto transp = [&](const float* W0, const float* W1, const float* W2, int nw, int K, int N) {
        transpose_w<<<dim3(N / 32, K / 32, nw), blk, 0, stream>>>(W0, W1, W2, wth, wtl, K, N);
    };

    cvt_split<<<(M * D) / 1024, blk, 0, stream>>>(x_in, xh, xl, M * D);
    cvt_split<<<(M * D) / 1024, blk, 0, stream>>>(enc, eh, el, M * D);

    const long SM = (long)S * S;
    const long S3 = (long)S * 3072;
    const long SD = (long)S * D;

    for (int i = 0; i < L; i++) {
        size_t wo = (size_t)i * D * D;
        // ---- self-attention (causal) ----
        transp(Wq1 + wo, Wk1 + wo, Wv1 + wo, 3, D, D);
        gemmBig(xh, xl, wth, wtl, qkvh, qkvl, nullptr, M, 3 * D, D, D, D, 3 * D);
        vtrans<<<dim3(D / 32, S / 32, 2 * BATCH), blk, 0, stream>>>(qkvh, qkvl, vth, vtl, 3 * D, 2 * D);
        gemm(qkvh, qkvl, qkvh + D, qkvl + D, scores, nullptr, nullptr, nullptr, 0.125f,
             S, S, D, 3 * D, 3 * D, S, S3, S3, SM, BATCH, 1);
        softmax_rows<<<dim3(S, BATCH), blk, 0, stream>>>(scores, ph, pl_, 1);
        gemm(ph, pl_, vth, vtl, nullptr, ath, atl, nullptr, 1.f,
             S, D, S, S, S, D, SM, SD, SD, BATCH, 2);
        transp(Wo1 + wo, nullptr, nullptr, 1, D, D);
        gemm(ath, atl, wth, wtl, yf, nullptr, nullptr, nullptr, 1.f,
             M, D, D, D, D, D, 0, 0, 0, 1, 0);
        ln_res<<<M, blk, 0, stream>>>((i == 0) ? x_in : xf, yf,
                                      g1 + (size_t)i * D, b1 + (size_t)i * D, xf, xh, xl);

        // ---- cross-attention (all visible) ----
        transp(Wq2 + wo, nullptr, nullptr, 1, D, D);
        gemm(xh, xl, wth, wtl, nullptr, qkvh, qkvl, nullptr, 1.f,
             M, D, D, D, D, 3 * D, 0, 0, 0, 1, 0);
        transp(Wk2 + wo, Wv2 + wo, nullptr, 2, D, D);
        gemm(eh, el, wth, wtl, nullptr, qkvh + D, qkvl + D, nullptr, 1.f,
             M, 2 * D, D, D, D, 3 * D, 0, 0, 0, 1, 0);
        vtrans<<<dim3(D / 32, S / 32, 2 * BATCH), blk, 0, stream>>>(qkvh, qkvl, vth, vtl, 3 * D, 2 * D);
        gemm(qkvh, qkvl, qkvh + D, qkvl + D, scores, nullptr, nullptr, nullptr, 0.125f,
             S, S, D, 3 * D, 3 * D, S, S3, S3, SM, BATCH, 0);
        softmax_rows<<<dim3(S, BATCH), blk, 0, stream>>>(scores, ph, pl_, 0);
        gemm(ph, pl_, vth, vtl, nullptr, ath, atl, nullptr, 1.f,
             S, D, S, S, S, D, SM, SD, SD, BATCH, 0);
        transp(Wo2 + wo, nullptr, nullptr, 1, D, D);
        gemm(ath, atl, wth, wtl, yf, nullptr, nullptr, nullptr, 1.f,
             M, D, D, D, D, D, 0, 0, 0, 1, 0);
        ln_res<<<M, blk, 0, stream>>>(xf, yf, g2 + (size_t)i * D, b2 + (size_t)i * D, xf, xh, xl);

        // ---- feedforward ----
        transp(Wf1 + (size_t)i * D * DFF, nullptr, nullptr, 1, D, DFF);
        gemmBig(xh, xl, wth, wtl, hph, hpl, bf1 + (size_t)i * DFF, M, DFF, D, D, D, DFF);
        transp(Wf2 + (size_t)i * DFF * D, nullptr, nullptr, 1, DFF, D);
        gemm(hph, hpl, wth, wtl, yf, nullptr, nullptr, bf2 + (size_t)i * D, 1.f,
             M, D, DFF, DFF, DFF, D, 0, 0, 0, 1, 0);
        float* lnout = (i == L - 1) ? (float*)d_out : xf;
        ln_res<<<M, blk, 0, stream>>>(xf, yf, g3 + (size_t)i * D, b3 + (size_t)i * D, lnout, xh, xl);
    }
}

// Round 15
// 3614.001 us; speedup vs baseline: 1.1790x; 1.1790x over previous
//
#include <hip/hip_runtime.h>

#define L 6
#define D 1024
#define DFF 4096
#define BATCH 4
#define S 1024

typedef __attribute__((ext_vector_type(4))) float f32x4;
typedef __attribute__((ext_vector_type(16))) float f32x16;
typedef __attribute__((ext_vector_type(8))) short short8;

__device__ __forceinline__ ushort f2bf(float f) {
    unsigned int u = __float_as_uint(f);
    u = u + 0x7FFF + ((u >> 16) & 1);
    return (ushort)(u >> 16);
}
__device__ __forceinline__ float bf2f(ushort u) {
    return __uint_as_float(((unsigned int)u) << 16);
}
__device__ __forceinline__ void gload16(const ushort* g, ushort* l) {
    __builtin_amdgcn_global_load_lds(
        (const __attribute__((address_space(1))) void*)g,
        (__attribute__((address_space(3))) void*)l, 16, 0, 0);
}

// ---------------- split f32 -> (hi, lo) bf16 planes ----------------
__global__ __launch_bounds__(256) void cvt_split(const float* __restrict__ in,
                                                 ushort* __restrict__ oh,
                                                 ushort* __restrict__ ol, int n) {
    int i = (blockIdx.x * 256 + threadIdx.x) * 4;
    if (i >= n) return;
    float4 v = *(const float4*)&in[i];
    ushort4 h, l;
    h.x = f2bf(v.x); l.x = f2bf(v.x - bf2f(h.x));
    h.y = f2bf(v.y); l.y = f2bf(v.y - bf2f(h.y));
    h.z = f2bf(v.z); l.z = f2bf(v.z - bf2f(h.z));
    h.w = f2bf(v.w); l.w = f2bf(v.w - bf2f(h.w));
    *(ushort4*)&oh[i] = h;
    *(ushort4*)&ol[i] = l;
}

// ------- transpose up to 3 weights [K,N] f32 -> stacked [z*N + n][K] h/l bf16 -------
__global__ __launch_bounds__(256) void transpose_w(const float* __restrict__ W0,
                                                   const float* __restrict__ W1,
                                                   const float* __restrict__ W2,
                                                   ushort* __restrict__ outh,
                                                   ushort* __restrict__ outl,
                                                   int K, int N) {
    const float* W = blockIdx.z == 0 ? W0 : (blockIdx.z == 1 ? W1 : W2);
    __shared__ float T[32][33];
    int n0 = blockIdx.x * 32, k0 = blockIdx.y * 32;
    int t = threadIdx.x;
    int r = t >> 3, c4 = (t & 7) * 4;
    float4 v = *(const float4*)&W[(size_t)(k0 + r) * N + n0 + c4];
    T[r][c4 + 0] = v.x; T[r][c4 + 1] = v.y; T[r][c4 + 2] = v.z; T[r][c4 + 3] = v.w;
    __syncthreads();
    float a0 = T[c4 + 0][r], a1 = T[c4 + 1][r], a2 = T[c4 + 2][r], a3 = T[c4 + 3][r];
    ushort4 h, l;
    h.x = f2bf(a0); l.x = f2bf(a0 - bf2f(h.x));
    h.y = f2bf(a1); l.y = f2bf(a1 - bf2f(h.y));
    h.z = f2bf(a2); l.z = f2bf(a2 - bf2f(h.z));
    h.w = f2bf(a3); l.w = f2bf(a3 - bf2f(h.w));
    size_t ob = ((size_t)blockIdx.z * N + n0 + r) * K + k0 + c4;
    *(ushort4*)&outh[ob] = h;
    *(ushort4*)&outl[ob] = l;
}

// ---------------- transpose V planes [b][s][3072-strided] -> [b][d][s] ----------------
__global__ __launch_bounds__(256) void vtrans(const ushort* __restrict__ inh,
                                              const ushort* __restrict__ inl,
                                              ushort* __restrict__ outh,
                                              ushort* __restrict__ outl,
                                              int ld_in, int col_off) {
    __shared__ ushort T[32][40];
    const int pz = blockIdx.z, b = pz >> 1;
    const ushort* in = (pz & 1) ? inl : inh;
    ushort* out = (pz & 1) ? outl : outh;
    const int d0 = blockIdx.x * 32, s0 = blockIdx.y * 32;
    const int t = threadIdx.x, r = t >> 3, c4 = (t & 7) * 4;
    ushort4 v = *(const ushort4*)&in[(size_t)(b * S + s0 + r) * ld_in + col_off + d0 + c4];
    T[r][c4 + 0] = v.x; T[r][c4 + 1] = v.y; T[r][c4 + 2] = v.z; T[r][c4 + 3] = v.w;
    __syncthreads();
    ushort4 o = {T[c4 + 0][r], T[c4 + 1][r], T[c4 + 2][r], T[c4 + 3][r]};
    *(ushort4*)&out[(size_t)(b * D + d0 + r) * S + s0 + c4] = o;
}

// -------- reduce 8 split-K f32 partials [8][1024][1024] -> h/l bf16 planes --------
__global__ __launch_bounds__(256) void reduce_split(const float* __restrict__ part,
                                                    ushort* __restrict__ oh,
                                                    ushort* __restrict__ ol) {
    int i = (blockIdx.x * 256 + threadIdx.x) * 4;
    float4 s = *(const float4*)&part[i];
#pragma unroll
    for (int z = 1; z < 8; z++) {
        float4 p = *(const float4*)&part[(size_t)z * 1048576 + i];
        s.x += p.x; s.y += p.y; s.z += p.z; s.w += p.w;
    }
    ushort4 h, l;
    h.x = f2bf(s.x); l.x = f2bf(s.x - bf2f(h.x));
    h.y = f2bf(s.y); l.y = f2bf(s.y - bf2f(h.y));
    h.z = f2bf(s.z); l.z = f2bf(s.z - bf2f(h.z));
    h.w = f2bf(s.w); l.w = f2bf(s.w - bf2f(h.w));
    *(ushort4*)&oh[i] = h;
    *(ushort4*)&ol[i] = l;
}

// -------- bias fold: out[n] = sum_j bf1[j] * Wf2[j][n] + bf2[n]  (f32 exact) --------
__global__ __launch_bounds__(256) void bias_fold(const float* __restrict__ bf1,
                                                 const float* __restrict__ Wf2,
                                                 const float* __restrict__ bf2,
                                                 float* __restrict__ out) {
    __shared__ float red[4][64];
    const int lane = threadIdx.x & 63, js = threadIdx.x >> 6;
    const int n = blockIdx.x * 64 + lane;
    float s = 0.f;
    const int j0 = js * 1024;
    for (int j = j0; j < j0 + 1024; j++) s += bf1[j] * Wf2[(size_t)j * D + n];
    red[js][lane] = s;
    __syncthreads();
    if (js == 0) out[n] = red[0][lane] + red[1][lane] + red[2][lane] + red[3][lane] + bf2[n];
}

// ============ gemm8: 256x256 deep-prefetch split-precision GEMM (big-N, z=1) ============
#define MFMA32(d, a, b) d = __builtin_amdgcn_mfma_f32_32x32x16_bf16(a, b, d, 0, 0, 0)
#define CLUSTER12(MB, A0H, A0L, A1H, A1L, B0H, B0L, B1H, B1L)                          \
    MFMA32(acc[MB][0], A0H, B0H); MFMA32(acc[MB][0], A0H, B0L);                        \
    MFMA32(acc[MB][0], A0L, B0H);                                                      \
    MFMA32(acc[MB][1], A0H, B1H); MFMA32(acc[MB][1], A0H, B1L);                        \
    MFMA32(acc[MB][1], A0L, B1H);                                                      \
    MFMA32(acc[MB + 1][0], A1H, B0H); MFMA32(acc[MB + 1][0], A1H, B0L);                \
    MFMA32(acc[MB + 1][0], A1L, B0H);                                                  \
    MFMA32(acc[MB + 1][1], A1H, B1H); MFMA32(acc[MB + 1][1], A1H, B1L);                \
    MFMA32(acc[MB + 1][1], A1L, B1H);

__global__ __launch_bounds__(512, 2) void gemm8(
    const ushort* __restrict__ Ah, const ushort* __restrict__ Al,
    const ushort* __restrict__ Bh, const ushort* __restrict__ Bl,
    ushort* __restrict__ Ch, ushort* __restrict__ Cl,
    const float* __restrict__ bias, float alpha,
    int M, int N, int K, int lda, int ldb, int ldc) {
    __shared__ ushort lds[65536];   // 128 KiB: [buf2][plane4][row256][col32]

    const int gx = gridDim.x, gy = gridDim.y;
    int nblk = gx * gy;
    int bid = blockIdx.y * gx + blockIdx.x;
    if ((nblk & 7) == 0) bid = (bid & 7) * (nblk >> 3) + (bid >> 3);
    const int bx = bid % gx, by = bid / gx;
    const int bm = by * 256, bn = bx * 256;

    const int tid = threadIdx.x, lane = tid & 63, w = tid >> 6;
    const int wr = w >> 2, wc = w & 3;
    const int l31 = lane & 31, hi = lane >> 5;

    f32x16 acc[4][2] = {};
    const int NT = K >> 5;

    auto stage_tile = [&](int kt) {
        const int bufo = (kt & 1) * 32768;
#pragma unroll
        for (int h = 0; h < 2; h++) {
            const int row = h * 128 + (w << 4) + (lane >> 2);
            const int ps = lane & 3;
            const int col = (kt << 5) + ((ps ^ ((row >> 1) & 3)) << 3);
            const int drow = h * 128 + (w << 4);
            gload16(Ah + (size_t)(bm + row) * lda + col, lds + bufo + 0 * 8192 + drow * 32);
            gload16(Al + (size_t)(bm + row) * lda + col, lds + bufo + 1 * 8192 + drow * 32);
            gload16(Bh + (size_t)(bn + row) * ldb + col, lds + bufo + 2 * 8192 + drow * 32);
            gload16(Bl + (size_t)(bn + row) * ldb + col, lds + bufo + 3 * 8192 + drow * 32);
        }
    };
    auto rdA = [&](int bufo, int mi, int pl, int ksub) -> short8 {
        const int row = wr * 128 + mi * 32 + l31;
        const int ps = (ksub * 2 + hi) ^ ((row >> 1) & 3);
        return *(const short8*)&lds[bufo + pl * 8192 + row * 32 + ps * 8];
    };
    auto rdB = [&](int bufo, int nj, int pl, int ksub) -> short8 {
        const int row = wc * 64 + nj * 32 + l31;
        const int ps = (ksub * 2 + hi) ^ ((row >> 1) & 3);
        return *(const short8*)&lds[bufo + (2 + pl) * 8192 + row * 32 + ps * 8];
    };

    stage_tile(0);
    if (NT > 1) stage_tile(1);

    for (int kt = 0; kt < NT; kt++) {
        const int bufo = (kt & 1) * 32768;
        if (kt + 1 < NT) {
            asm volatile("s_waitcnt vmcnt(8)" ::: "memory");
        } else {
            asm volatile("s_waitcnt vmcnt(0)" ::: "memory");
        }
        __builtin_amdgcn_s_barrier();
        __builtin_amdgcn_sched_barrier(0);
        short8 b00h = rdB(bufo, 0, 0, 0), b00l = rdB(bufo, 0, 1, 0);
        short8 b10h = rdB(bufo, 1, 0, 0), b10l = rdB(bufo, 1, 1, 0);
        short8 a00h = rdA(bufo, 0, 0, 0), a00l = rdA(bufo, 0, 1, 0);
        short8 a10h = rdA(bufo, 1, 0, 0), a10l = rdA(bufo, 1, 1, 0);
        short8 a20h = rdA(bufo, 2, 0, 0), a20l = rdA(bufo, 2, 1, 0);
        short8 a30h = rdA(bufo, 3, 0, 0), a30l = rdA(bufo, 3, 1, 0);
        short8 b01h = rdB(bufo, 0, 0, 1), b01l = rdB(bufo, 0, 1, 1);
        short8 b11h = rdB(bufo, 1, 0, 1), b11l = rdB(bufo, 1, 1, 1);
        short8 a01h = rdA(bufo, 0, 0, 1), a01l = rdA(bufo, 0, 1, 1);
        short8 a11h = rdA(bufo, 1, 0, 1), a11l = rdA(bufo, 1, 1, 1);
        short8 a21h = rdA(bufo, 2, 0, 1), a21l = rdA(bufo, 2, 1, 1);
        short8 a31h = rdA(bufo, 3, 0, 1), a31l = rdA(bufo, 3, 1, 1);
        __builtin_amdgcn_s_setprio(1);
        CLUSTER12(0, a00h, a00l, a10h, a10l, b00h, b00l, b10h, b10l);
        CLUSTER12(2, a20h, a20l, a30h, a30l, b00h, b00l, b10h, b10l);
        CLUSTER12(0, a01h, a01l, a11h, a11l, b01h, b01l, b11h, b11l);
        __builtin_amdgcn_s_setprio(0);
        asm volatile("s_waitcnt lgkmcnt(0)" ::: "memory");
        __builtin_amdgcn_sched_barrier(0);
        __builtin_amdgcn_s_barrier();
        if (kt + 2 < NT) stage_tile(kt + 2);
        __builtin_amdgcn_s_setprio(1);
        CLUSTER12(2, a21h, a21l, a31h, a31l, b01h, b01l, b11h, b11l);
        __builtin_amdgcn_s_setprio(0);
    }

#pragma unroll
    for (int mi = 0; mi < 4; mi++) {
#pragma unroll
        for (int nj = 0; nj < 2; nj++) {
            const int n = bn + wc * 64 + nj * 32 + l31;
            const float bv = bias ? bias[n] : 0.f;
#pragma unroll
            for (int r = 0; r < 16; r++) {
                const int m = bm + wr * 128 + mi * 32 + (r & 3) + 8 * (r >> 2) + 4 * hi;
                float v = acc[mi][nj][r] * alpha + bv;
                const size_t ci = (size_t)m * ldc + n;
                ushort h = f2bf(v);
                Ch[ci] = h;
                Cl[ci] = f2bf(v - bf2f(h));
            }
        }
    }
}

// ---------------- gemm3: 128x128 split-precision GEMM (round-8 proven) ----------------
// triMode: 0 none; 1 = causal scores (skip bx>by); 2 = causal PV (cap K-tiles at 2*by+2)
__global__ __launch_bounds__(256) void gemm3(
    const ushort* __restrict__ Ah, const ushort* __restrict__ Al,
    const ushort* __restrict__ Bh, const ushort* __restrict__ Bl,
    float* __restrict__ Cf, ushort* __restrict__ Ch, ushort* __restrict__ Cl,
    const float* __restrict__ bias, float alpha,
    int M, int N, int K, int lda, int ldb, int ldc,
    long sA, long sB, long sC, int triMode) {
    __shared__ ushort lds[4 * 128 * 64];
    ushort* Ash = lds;
    ushort* Asl = lds + 128 * 64;
    ushort* Bsh = lds + 2 * 128 * 64;
    ushort* Bsl = lds + 3 * 128 * 64;

    const int gx = gridDim.x, gy = gridDim.y;
    int nblk = gx * gy * gridDim.z;
    int bid = (blockIdx.z * gy + blockIdx.y) * gx + blockIdx.x;
    if ((nblk & 7) == 0) bid = (bid & 7) * (nblk >> 3) + (bid >> 3);
    const int bx = bid % gx;
    int rem = bid / gx;
    const int by = rem % gy;
    const int z = rem / gy;

    if (triMode == 1 && bx > by) return;
    int NT = K >> 6;
    if (triMode == 2) {
        int cap = 2 * by + 2;
        if (cap < NT) NT = cap;
    }

    const int bm = by * 128, bn = bx * 128;
    const ushort* A0 = Ah + (size_t)z * sA;
    const ushort* A1 = Al + (size_t)z * sA;
    const ushort* B0 = Bh + (size_t)z * sB;
    const ushort* B1 = Bl + (size_t)z * sB;
    const size_t coff = (size_t)z * sC;

    const int tid = threadIdx.x, lane = tid & 63;
    const int wid = tid >> 6, wr = wid >> 1, wc = wid & 1;
    const int lr = lane & 15, lg = lane >> 4;

    f32x4 acc[4][4] = {};

    for (int kt = 0; kt < NT; kt++) {
        const int k0 = kt << 6;
        if (kt) __syncthreads();
#pragma unroll
        for (int c = 0; c < 4; c++) {
            const int idx = c * 256 + tid;
            const int row = idx >> 3;
            const int col = (((idx & 7) ^ (row & 7)) * 8);
            const int lbase = (c * 256 + (tid & 192)) * 8;
            const size_t aoff = (size_t)(bm + row) * lda + k0 + col;
            const size_t boff = (size_t)(bn + row) * ldb + k0 + col;
            gload16(A0 + aoff, Ash + lbase);
            gload16(A1 + aoff, Asl + lbase);
            gload16(B0 + boff, Bsh + lbase);
            gload16(B1 + boff, Bsl + lbase);
        }
        asm volatile("s_waitcnt vmcnt(0)" ::: "memory");
        __syncthreads();
#pragma unroll
        for (int ks = 0; ks < 2; ks++) {
            short8 afh[4], afl[4], bfh[4], bfl[4];
#pragma unroll
            for (int i = 0; i < 4; i++) {
                const int arow = wr * 64 + i * 16 + lr;
                const int brow = wc * 64 + i * 16 + lr;
                const int ar = arow * 64 + ((ks * 4 + lg) ^ (arow & 7)) * 8;
                const int br = brow * 64 + ((ks * 4 + lg) ^ (brow & 7)) * 8;
                afh[i] = *(const short8*)&Ash[ar];
                afl[i] = *(const short8*)&Asl[ar];
                bfh[i] = *(const short8*)&Bsh[br];
                bfl[i] = *(const short8*)&Bsl[br];
            }
#pragma unroll
            for (int i = 0; i < 4; i++)
#pragma unroll
                for (int j = 0; j < 4; j++) {
                    acc[i][j] = __builtin_amdgcn_mfma_f32_16x16x32_bf16(afh[i], bfh[j], acc[i][j], 0, 0, 0);
                    acc[i][j] = __builtin_amdgcn_mfma_f32_16x16x32_bf16(afh[i], bfl[j], acc[i][j], 0, 0, 0);
                    acc[i][j] = __builtin_amdgcn_mfma_f32_16x16x32_bf16(afl[i], bfh[j], acc[i][j], 0, 0, 0);
                }
        }
    }
#pragma unroll
    for (int j = 0; j < 4; j++) {
        const int n = bn + wc * 64 + j * 16 + lr;
        const float bv = bias ? bias[n] : 0.f;
#pragma unroll
        for (int i = 0; i < 4; i++) {
#pragma unroll
            for (int r = 0; r < 4; r++) {
                const int m = bm + wr * 64 + i * 16 + lg * 4 + r;
                float v = acc[i][j][r] * alpha + bv;
                const size_t ci = coff + (size_t)m * ldc + n;
                if (Cf) Cf[ci] = v;
                if (Ch) {
                    ushort h = f2bf(v);
                    Ch[ci] = h;
                    Cl[ci] = f2bf(v - bf2f(h));
                }
            }
        }
    }
}

// ---------------- row softmax (f32 in, h/l bf16 planes out) ----------------
__global__ __launch_bounds__(256) void softmax_rows(const float* __restrict__ Sc,
                                                    ushort* __restrict__ Ph,
                                                    ushort* __restrict__ Pl, int causal) {
    __shared__ float red[4];
    int q = blockIdx.x, b = blockIdx.y;
    size_t base = ((size_t)b * S + q) * S;
    int valid = causal ? (q + 1) : S;
    int tid = threadIdx.x;
    float v[4];
    float mx = -3e38f;
#pragma unroll
    for (int j = 0; j < 4; j++) {
        int c = tid + j * 256;
        float x = (c < valid) ? Sc[base + c] : -3e38f;
        v[j] = x;
        mx = fmaxf(mx, v[j]);
    }
    for (int o = 32; o; o >>= 1) mx = fmaxf(mx, __shfl_xor(mx, o));
    if ((tid & 63) == 0) red[tid >> 6] = mx;
    __syncthreads();
    mx = fmaxf(fmaxf(red[0], red[1]), fmaxf(red[2], red[3]));
    float s = 0.f;
#pragma unroll
    for (int j = 0; j < 4; j++) {
        int c = tid + j * 256;
        float e = (c < valid) ? __expf(v[j] - mx) : 0.f;
        v[j] = e;
        s += e;
    }
    for (int o = 32; o; o >>= 1) s += __shfl_xor(s, o);
    __syncthreads();
    if ((tid & 63) == 0) red[tid >> 6] = s;
    __syncthreads();
    s = red[0] + red[1] + red[2] + red[3];
    float inv = 1.0f / s;
#pragma unroll
    for (int j = 0; j < 4; j++) {
        int c = tid + j * 256;
        float p = v[j] * inv;
        ushort h = f2bf(p);
        Ph[base + c] = h;
        Pl[base + c] = f2bf(p - bf2f(h));
    }
}

// ---------------- residual + layernorm (f32 in, f32 + h/l planes out) ----------------
__global__ __launch_bounds__(256) void ln_res(const float* __restrict__ xin,
                                              const float* __restrict__ y,
                                              const float* __restrict__ g,
                                              const float* __restrict__ bta,
                                              float* __restrict__ xof,
                                              ushort* __restrict__ xh,
                                              ushort* __restrict__ xl) {
    __shared__ float red[4];
    int row = blockIdx.x;
    size_t base = (size_t)row * D;
    int tid = threadIdx.x;
    int c0 = tid * 4;
    float4 xv = *(const float4*)&xin[base + c0];
    float4 yv = *(const float4*)&y[base + c0];
    float t[4] = {xv.x + yv.x, xv.y + yv.y, xv.z + yv.z, xv.w + yv.w};
    float s = t[0] + t[1] + t[2] + t[3];
    for (int o = 32; o; o >>= 1) s += __shfl_xor(s, o);
    if ((tid & 63) == 0) red[tid >> 6] = s;
    __syncthreads();
    s = red[0] + red[1] + red[2] + red[3];
    float mean = s * (1.0f / D);
    float vs = 0.f;
#pragma unroll
    for (int j = 0; j < 4; j++) {
        float dd = t[j] - mean;
        vs += dd * dd;
    }
    for (int o = 32; o; o >>= 1) vs += __shfl_xor(vs, o);
    __syncthreads();
    if ((tid & 63) == 0) red[tid >> 6] = vs;
    __syncthreads();
    vs = red[0] + red[1] + red[2] + red[3];
    float inv = rsqrtf(vs * (1.0f / D) + 1e-5f);
    float4 gv = *(const float4*)&g[c0];
    float4 bv = *(const float4*)&bta[c0];
    float o0 = (t[0] - mean) * inv * gv.x + bv.x;
    float o1 = (t[1] - mean) * inv * gv.y + bv.y;
    float o2 = (t[2] - mean) * inv * gv.z + bv.z;
    float o3 = (t[3] - mean) * inv * gv.w + bv.w;
    float4 fo = {o0, o1, o2, o3};
    *(float4*)&xof[base + c0] = fo;
    ushort4 h, l;
    h.x = f2bf(o0); l.x = f2bf(o0 - bf2f(h.x));
    h.y = f2bf(o1); l.y = f2bf(o1 - bf2f(h.y));
    h.z = f2bf(o2); l.z = f2bf(o2 - bf2f(h.z));
    h.w = f2bf(o3); l.w = f2bf(o3 - bf2f(h.w));
    *(ushort4*)&xh[base + c0] = h;
    *(ushort4*)&xl[base + c0] = l;
}

__global__ __launch_bounds__(256) void fill_f32(float* out, float v, int n) {
    int i = (blockIdx.x * 256 + threadIdx.x) * 4;
    if (i >= n) return;
    float4 f = {v, v, v, v};
    *(float4*)&out[i] = f;
}

extern "C" void kernel_launch(void* const* d_in, const int* in_sizes, int n_in,
                              void* d_out, int out_size, void* d_ws, size_t ws_size,
                              hipStream_t stream) {
    dim3 blk(256);
    const int M = BATCH * S;  // 4096
    const int fill_blocks = (out_size / 4 + 255) / 256;

    int base = n_in - 18;
    bool layout_ok = (base >= 2) && (out_size == M * D) &&
                     (in_sizes[0] == M * D) && (in_sizes[1] == M * D) &&
                     (in_sizes[base] == L * D * D) && (in_sizes[base + 4] == L * D) &&
                     (in_sizes[base + 12] == L * D * DFF) && (in_sizes[base + 13] == L * DFF);
    if (!layout_ok) {
        fill_f32<<<fill_blocks, blk, 0, stream>>>((float*)d_out, 9000.f, out_size);
        return;
    }
    const float* x_in = (const float*)d_in[0];
    const float* enc  = (const float*)d_in[1];
    const float* Wq1 = (const float*)d_in[base + 0];
    const float* Wk1 = (const float*)d_in[base + 1];
    const float* Wv1 = (const float*)d_in[base + 2];
    const float* Wo1 = (const float*)d_in[base + 3];
    const float* g1  = (const float*)d_in[base + 4];
    const float* b1  = (const float*)d_in[base + 5];
    const float* Wq2 = (const float*)d_in[base + 6];
    const float* Wk2 = (const float*)d_in[base + 7];
    const float* Wv2 = (const float*)d_in[base + 8];
    const float* Wo2 = (const float*)d_in[base + 9];
    const float* g2  = (const float*)d_in[base + 10];
    const float* b2  = (const float*)d_in[base + 11];
    const float* Wf1 = (const float*)d_in[base + 12];
    const float* bf1 = (const float*)d_in[base + 13];
    const float* Wf2 = (const float*)d_in[base + 14];
    const float* bf2 = (const float*)d_in[base + 15];
    const float* g3  = (const float*)d_in[base + 16];
    const float* b3  = (const float*)d_in[base + 17];

    const size_t PL = (size_t)M * D * 2;   // 8 MiB bf16 plane
    const size_t required = 22 * PL;       // 176 MiB
    if (ws_size < required) {
        fill_f32<<<fill_blocks, blk, 0, stream>>>((float*)d_out, 500.f, out_size);
        return;
    }

    char* ws = (char*)d_ws;
    size_t off = 0;
    auto carve = [&](size_t bytes) -> char* {
        char* p = ws + off;
        off += (bytes + 255) & ~(size_t)255;
        return p;
    };
    float*  xf = (float*)carve(2 * PL);
    ushort* xh = (ushort*)carve(PL);
    ushort* xl = (ushort*)carve(PL);
    ushort* eh = (ushort*)carve(PL);
    ushort* el = (ushort*)carve(PL);
    char*   clu = carve(10 * PL);
    ushort* qkvh = (ushort*)clu;                 // 3 PL (4096 x 3072)
    ushort* qkvl = (ushort*)(clu + 3 * PL);      // 3 PL
    ushort* vth  = (ushort*)(clu + 6 * PL);      // [b][d][s]
    ushort* vtl  = (ushort*)(clu + 7 * PL);
    float*  scores = (float*)(clu + 8 * PL);     // 2 PL f32, aliases at-planes
    ushort* ath  = (ushort*)(clu + 8 * PL);
    ushort* atl  = (ushort*)(clu + 9 * PL);
    // FFN-time aliases (attention buffers dead then):
    float*  wpart = (float*)clu;                 // 8 x 1024x1024 f32 partials (32 MiB)
    ushort* wpH   = (ushort*)(clu + 4 * PL);     // W'^T hi plane (2 MiB)
    ushort* wpL   = (ushort*)(clu + 4 * PL + 2097152);
    float*  bprime = (float*)(clu + 9 * PL);     // folded bias (4 KiB)
    ushort* ph = (ushort*)carve(PL);
    ushort* pl_ = (ushort*)carve(PL);
    float*  yf = (float*)carve(2 * PL);
    ushort* wth = (ushort*)carve(PL);
    ushort* wtl = (ushort*)carve(PL);

    auto gemm = [&](const ushort* Ah, const ushort* Al, const ushort* Bh, const ushort* Bl,
                    float* Cf, ushort* Ch, ushort* Cl, const float* bias, float alpha,
                    int gm, int gn, int gk, int lda, int ldb, int ldc,
                    long sA, long sB, long sC, int batch, int tri) {
        dim3 g(gn / 128, gm / 128, batch);
        gemm3<<<g, blk, 0, stream>>>(Ah, Al, Bh, Bl, Cf, Ch, Cl, bias, alpha,
                                     gm, gn, gk, lda, ldb, ldc, sA, sB, sC, tri);
    };
    auto gemmBig = [&](const ushort* Ah, const ushort* Al, const ushort* Bh, const ushort* Bl,
                       ushort* Ch, ushort* Cl, const float* bias,
                       int gm, int gn, int gk, int lda, int ldb, int ldc) {
        dim3 g(gn / 256, gm / 256);
        gemm8<<<g, dim3(512), 0, stream>>>(Ah, Al, Bh, Bl, Ch, Cl, bias, 1.f,
                                           gm, gn, gk, lda, ldb, ldc);
    };
    auto transp = [&](const float* W0, const float* W1, const float* W2, int nw, int K, int N) {
        transpose_w<<<dim3(N / 32, K / 32, nw), blk, 0, stream>>>(W0, W1, W2, wth, wtl, K, N);
    };

    cvt_split<<<(M * D) / 1024, blk, 0, stream>>>(x_in, xh, xl, M * D);
    cvt_split<<<(M * D) / 1024, blk, 0, stream>>>(enc, eh, el, M * D);

    const long SM = (long)S * S;
    const long S3 = (long)S * 3072;
    const long SD = (long)S * D;

    for (int i = 0; i < L; i++) {
        size_t wo = (size_t)i * D * D;
        // ---- self-attention (causal) ----
        transp(Wq1 + wo, Wk1 + wo, Wv1 + wo, 3, D, D);
        gemmBig(xh, xl, wth, wtl, qkvh, qkvl, nullptr, M, 3 * D, D, D, D, 3 * D);
        vtrans<<<dim3(D / 32, S / 32, 2 * BATCH), blk, 0, stream>>>(qkvh, qkvl, vth, vtl, 3 * D, 2 * D);
        gemm(qkvh, qkvl, qkvh + D, qkvl + D, scores, nullptr, nullptr, nullptr, 0.125f,
             S, S, D, 3 * D, 3 * D, S, S3, S3, SM, BATCH, 1);
        softmax_rows<<<dim3(S, BATCH), blk, 0, stream>>>(scores, ph, pl_, 1);
        gemm(ph, pl_, vth, vtl, nullptr, ath, atl, nullptr, 1.f,
             S, D, S, S, S, D, SM, SD, SD, BATCH, 2);
        transp(Wo1 + wo, nullptr, nullptr, 1, D, D);
        gemm(ath, atl, wth, wtl, yf, nullptr, nullptr, nullptr, 1.f,
             M, D, D, D, D, D, 0, 0, 0, 1, 0);
        ln_res<<<M, blk, 0, stream>>>((i == 0) ? x_in : xf, yf,
                                      g1 + (size_t)i * D, b1 + (size_t)i * D, xf, xh, xl);

        // ---- cross-attention (all visible) ----
        transp(Wq2 + wo, nullptr, nullptr, 1, D, D);
        gemm(xh, xl, wth, wtl, nullptr, qkvh, qkvl, nullptr, 1.f,
             M, D, D, D, D, 3 * D, 0, 0, 0, 1, 0);
        transp(Wk2 + wo, Wv2 + wo, nullptr, 2, D, D);
        gemm(eh, el, wth, wtl, nullptr, qkvh + D, qkvl + D, nullptr, 1.f,
             M, 2 * D, D, D, D, 3 * D, 0, 0, 0, 1, 0);
        vtrans<<<dim3(D / 32, S / 32, 2 * BATCH), blk, 0, stream>>>(qkvh, qkvl, vth, vtl, 3 * D, 2 * D);
        gemm(qkvh, qkvl, qkvh + D, qkvl + D, scores, nullptr, nullptr, nullptr, 0.125f,
             S, S, D, 3 * D, 3 * D, S, S3, S3, SM, BATCH, 0);
        softmax_rows<<<dim3(S, BATCH), blk, 0, stream>>>(scores, ph, pl_, 0);
        gemm(ph, pl_, vth, vtl, nullptr, ath, atl, nullptr, 1.f,
             S, D, S, S, S, D, SM, SD, SD, BATCH, 0);
        transp(Wo2 + wo, nullptr, nullptr, 1, D, D);
        gemm(ath, atl, wth, wtl, yf, nullptr, nullptr, nullptr, 1.f,
             M, D, D, D, D, D, 0, 0, 0, 1, 0);
        ln_res<<<M, blk, 0, stream>>>(xf, yf, g2 + (size_t)i * D, b2 + (size_t)i * D, xf, xh, xl);

        // ---- feedforward (collapsed: y = x @ (Wf1@Wf2) + (bf1@Wf2 + bf2)) ----
        const float* Wf1i = Wf1 + (size_t)i * D * DFF;
        const float* Wf2i = Wf2 + (size_t)i * DFF * D;
        // W'^T = Wf2^T @ Wf1^T : A = transpose(Wf2) [D][DFF], Bt = Wf1 as-is [D][DFF]
        transp(Wf2i, nullptr, nullptr, 1, DFF, D);                       // wth/wtl = Wf2^T
        cvt_split<<<(D * DFF) / 1024, blk, 0, stream>>>(Wf1i, ph, pl_, D * DFF);
        // split-K x8: C_z[a,b] = sum_{j in chunk z} Wf2^T[a,j] * Wf1[b,j]
        gemm(wth, wtl, ph, pl_, wpart, nullptr, nullptr, nullptr, 1.f,
             1024, 1024, 512, DFF, DFF, 1024, 512, 512, 1048576, 8, 0);
        reduce_split<<<1024, blk, 0, stream>>>(wpart, wpH, wpL);
        bias_fold<<<16, blk, 0, stream>>>(bf1 + (size_t)i * DFF, Wf2i,
                                          bf2 + (size_t)i * D, bprime);
        gemm(xh, xl, wpH, wpL, yf, nullptr, nullptr, bprime, 1.f,
             M, D, D, D, D, D, 0, 0, 0, 1, 0);
        ln_res<<<M, blk, 0, stream>>>(xf, yf, g3 + (size_t)i * D, b3 + (size_t)i * D,
                                      (i == L - 1) ? (float*)d_out : xf, xh, xl);
    }
}

// Round 16
// 2975.529 us; speedup vs baseline: 1.4319x; 1.2146x over previous
//
#include <hip/hip_runtime.h>

#define L 6
#define D 1024
#define DFF 4096
#define BATCH 4
#define S 1024

typedef __attribute__((ext_vector_type(4))) float f32x4;
typedef __attribute__((ext_vector_type(8))) short short8;

__device__ __forceinline__ ushort f2bf(float f) {
    unsigned int u = __float_as_uint(f);
    u = u + 0x7FFF + ((u >> 16) & 1);
    return (ushort)(u >> 16);
}
__device__ __forceinline__ float bf2f(ushort u) {
    return __uint_as_float(((unsigned int)u) << 16);
}
__device__ __forceinline__ void gload16(const ushort* g, ushort* l) {
    __builtin_amdgcn_global_load_lds(
        (const __attribute__((address_space(1))) void*)g,
        (__attribute__((address_space(3))) void*)l, 16, 0, 0);
}

// ---------------- split f32 -> (hi, lo) bf16 planes ----------------
__global__ __launch_bounds__(256) void cvt_split(const float* __restrict__ in,
                                                 ushort* __restrict__ oh,
                                                 ushort* __restrict__ ol, int n) {
    int i = (blockIdx.x * 256 + threadIdx.x) * 4;
    if (i >= n) return;
    float4 v = *(const float4*)&in[i];
    ushort4 h, l;
    h.x = f2bf(v.x); l.x = f2bf(v.x - bf2f(h.x));
    h.y = f2bf(v.y); l.y = f2bf(v.y - bf2f(h.y));
    h.z = f2bf(v.z); l.z = f2bf(v.z - bf2f(h.z));
    h.w = f2bf(v.w); l.w = f2bf(v.w - bf2f(h.w));
    *(ushort4*)&oh[i] = h;
    *(ushort4*)&ol[i] = l;
}

// ------- transpose weight [K,N] f32 -> [N,K] h/l bf16 -------
__global__ __launch_bounds__(256) void transpose_w(const float* __restrict__ W,
                                                   ushort* __restrict__ outh,
                                                   ushort* __restrict__ outl,
                                                   int K, int N) {
    __shared__ float T[32][33];
    int n0 = blockIdx.x * 32, k0 = blockIdx.y * 32;
    int t = threadIdx.x;
    int r = t >> 3, c4 = (t & 7) * 4;
    float4 v = *(const float4*)&W[(size_t)(k0 + r) * N + n0 + c4];
    T[r][c4 + 0] = v.x; T[r][c4 + 1] = v.y; T[r][c4 + 2] = v.z; T[r][c4 + 3] = v.w;
    __syncthreads();
    float a0 = T[c4 + 0][r], a1 = T[c4 + 1][r], a2 = T[c4 + 2][r], a3 = T[c4 + 3][r];
    ushort4 h, l;
    h.x = f2bf(a0); l.x = f2bf(a0 - bf2f(h.x));
    h.y = f2bf(a1); l.y = f2bf(a1 - bf2f(h.y));
    h.z = f2bf(a2); l.z = f2bf(a2 - bf2f(h.z));
    h.w = f2bf(a3); l.w = f2bf(a3 - bf2f(h.w));
    size_t ob = (size_t)(n0 + r) * K + k0 + c4;
    *(ushort4*)&outh[ob] = h;
    *(ushort4*)&outl[ob] = l;
}

// ---------------- transpose vo planes [b][s][2048-strided] -> [b][d][s] ----------------
__global__ __launch_bounds__(256) void vtrans(const ushort* __restrict__ inh,
                                              const ushort* __restrict__ inl,
                                              ushort* __restrict__ outh,
                                              ushort* __restrict__ outl,
                                              int ld_in, int col_off) {
    __shared__ ushort T[32][40];
    const int pz = blockIdx.z, b = pz >> 1;
    const ushort* in = (pz & 1) ? inl : inh;
    ushort* out = (pz & 1) ? outl : outh;
    const int d0 = blockIdx.x * 32, s0 = blockIdx.y * 32;
    const int t = threadIdx.x, r = t >> 3, c4 = (t & 7) * 4;
    ushort4 v = *(const ushort4*)&in[(size_t)(b * S + s0 + r) * ld_in + col_off + d0 + c4];
    T[r][c4 + 0] = v.x; T[r][c4 + 1] = v.y; T[r][c4 + 2] = v.z; T[r][c4 + 3] = v.w;
    __syncthreads();
    ushort4 o = {T[c4 + 0][r], T[c4 + 1][r], T[c4 + 2][r], T[c4 + 3][r]};
    *(ushort4*)&out[(size_t)(b * D + d0 + r) * S + s0 + c4] = o;
}

// -------- reduce 8 split-K f32 partials [8][1024][1024] -> h/l bf16 planes --------
__global__ __launch_bounds__(256) void reduce_split(const float* __restrict__ part,
                                                    ushort* __restrict__ oh,
                                                    ushort* __restrict__ ol) {
    int i = (blockIdx.x * 256 + threadIdx.x) * 4;
    float4 s = *(const float4*)&part[i];
#pragma unroll
    for (int z = 1; z < 8; z++) {
        float4 p = *(const float4*)&part[(size_t)z * 1048576 + i];
        s.x += p.x; s.y += p.y; s.z += p.z; s.w += p.w;
    }
    ushort4 h, l;
    h.x = f2bf(s.x); l.x = f2bf(s.x - bf2f(h.x));
    h.y = f2bf(s.y); l.y = f2bf(s.y - bf2f(h.y));
    h.z = f2bf(s.z); l.z = f2bf(s.z - bf2f(h.z));
    h.w = f2bf(s.w); l.w = f2bf(s.w - bf2f(h.w));
    *(ushort4*)&oh[i] = h;
    *(ushort4*)&ol[i] = l;
}

// -------- bias fold: out[n] = sum_j bf1[j] * Wf2[j][n] + bf2[n] --------
__global__ __launch_bounds__(256) void bias_fold(const float* __restrict__ bf1,
                                                 const float* __restrict__ Wf2,
                                                 const float* __restrict__ bf2,
                                                 float* __restrict__ out) {
    __shared__ float red[4][64];
    const int lane = threadIdx.x & 63, js = threadIdx.x >> 6;
    const int n = blockIdx.x * 64 + lane;
    float s = 0.f;
    const int j0 = js * 1024;
    for (int j = j0; j < j0 + 1024; j++) s += bf1[j] * Wf2[(size_t)j * D + n];
    red[js][lane] = s;
    __syncthreads();
    if (js == 0) out[n] = red[0][lane] + red[1][lane] + red[2][lane] + red[3][lane] + bf2[n];
}

// ---------------- gemm3: 128x128 split-precision GEMM (proven) ----------------
// triMode: 0 none; 1 = causal scores (skip bx>by); 2 = causal PV (cap K-tiles)
__global__ __launch_bounds__(256) void gemm3(
    const ushort* __restrict__ Ah, const ushort* __restrict__ Al,
    const ushort* __restrict__ Bh, const ushort* __restrict__ Bl,
    float* __restrict__ Cf, ushort* __restrict__ Ch, ushort* __restrict__ Cl,
    const float* __restrict__ bias, float alpha,
    int M, int N, int K, int lda, int ldb, int ldc,
    long sA, long sB, long sC, int triMode) {
    __shared__ ushort lds[4 * 128 * 64];
    ushort* Ash = lds;
    ushort* Asl = lds + 128 * 64;
    ushort* Bsh = lds + 2 * 128 * 64;
    ushort* Bsl = lds + 3 * 128 * 64;

    const int gx = gridDim.x, gy = gridDim.y;
    int nblk = gx * gy * gridDim.z;
    int bid = (blockIdx.z * gy + blockIdx.y) * gx + blockIdx.x;
    if ((nblk & 7) == 0) bid = (bid & 7) * (nblk >> 3) + (bid >> 3);
    const int bx = bid % gx;
    int rem = bid / gx;
    const int by = rem % gy;
    const int z = rem / gy;

    if (triMode == 1 && bx > by) return;
    int NT = K >> 6;
    if (triMode == 2) {
        int cap = 2 * by + 2;
        if (cap < NT) NT = cap;
    }

    const int bm = by * 128, bn = bx * 128;
    const ushort* A0 = Ah + (size_t)z * sA;
    const ushort* A1 = Al + (size_t)z * sA;
    const ushort* B0 = Bh + (size_t)z * sB;
    const ushort* B1 = Bl + (size_t)z * sB;
    const size_t coff = (size_t)z * sC;

    const int tid = threadIdx.x, lane = tid & 63;
    const int wid = tid >> 6, wr = wid >> 1, wc = wid & 1;
    const int lr = lane & 15, lg = lane >> 4;

    f32x4 acc[4][4] = {};

    for (int kt = 0; kt < NT; kt++) {
        const int k0 = kt << 6;
        if (kt) __syncthreads();
#pragma unroll
        for (int c = 0; c < 4; c++) {
            const int idx = c * 256 + tid;
            const int row = idx >> 3;
            const int col = (((idx & 7) ^ (row & 7)) * 8);
            const int lbase = (c * 256 + (tid & 192)) * 8;
            const size_t aoff = (size_t)(bm + row) * lda + k0 + col;
            const size_t boff = (size_t)(bn + row) * ldb + k0 + col;
            gload16(A0 + aoff, Ash + lbase);
            gload16(A1 + aoff, Asl + lbase);
            gload16(B0 + boff, Bsh + lbase);
            gload16(B1 + boff, Bsl + lbase);
        }
        asm volatile("s_waitcnt vmcnt(0)" ::: "memory");
        __syncthreads();
#pragma unroll
        for (int ks = 0; ks < 2; ks++) {
            short8 afh[4], afl[4], bfh[4], bfl[4];
#pragma unroll
            for (int i = 0; i < 4; i++) {
                const int arow = wr * 64 + i * 16 + lr;
                const int brow = wc * 64 + i * 16 + lr;
                const int ar = arow * 64 + ((ks * 4 + lg) ^ (arow & 7)) * 8;
                const int br = brow * 64 + ((ks * 4 + lg) ^ (brow & 7)) * 8;
                afh[i] = *(const short8*)&Ash[ar];
                afl[i] = *(const short8*)&Asl[ar];
                bfh[i] = *(const short8*)&Bsh[br];
                bfl[i] = *(const short8*)&Bsl[br];
            }
#pragma unroll
            for (int i = 0; i < 4; i++)
#pragma unroll
                for (int j = 0; j < 4; j++) {
                    acc[i][j] = __builtin_amdgcn_mfma_f32_16x16x32_bf16(afh[i], bfh[j], acc[i][j], 0, 0, 0);
                    acc[i][j] = __builtin_amdgcn_mfma_f32_16x16x32_bf16(afh[i], bfl[j], acc[i][j], 0, 0, 0);
                    acc[i][j] = __builtin_amdgcn_mfma_f32_16x16x32_bf16(afl[i], bfh[j], acc[i][j], 0, 0, 0);
                }
        }
    }
#pragma unroll
    for (int j = 0; j < 4; j++) {
        const int n = bn + wc * 64 + j * 16 + lr;
        const float bv = bias ? bias[n] : 0.f;
#pragma unroll
        for (int i = 0; i < 4; i++) {
#pragma unroll
            for (int r = 0; r < 4; r++) {
                const int m = bm + wr * 64 + i * 16 + lg * 4 + r;
                float v = acc[i][j][r] * alpha + bv;
                const size_t ci = coff + (size_t)m * ldc + n;
                if (Cf) Cf[ci] = v;
                if (Ch) {
                    ushort h = f2bf(v);
                    Ch[ci] = h;
                    Cl[ci] = f2bf(v - bf2f(h));
                }
            }
        }
    }
}

// ---------------- row softmax (f32 in, h/l bf16 planes out) ----------------
__global__ __launch_bounds__(256) void softmax_rows(const float* __restrict__ Sc,
                                                    ushort* __restrict__ Ph,
                                                    ushort* __restrict__ Pl, int causal) {
    __shared__ float red[4];
    int q = blockIdx.x, b = blockIdx.y;
    size_t base = ((size_t)b * S + q) * S;
    int valid = causal ? (q + 1) : S;
    int tid = threadIdx.x;
    float v[4];
    float mx = -3e38f;
#pragma unroll
    for (int j = 0; j < 4; j++) {
        int c = tid + j * 256;
        float x = (c < valid) ? Sc[base + c] : -3e38f;
        v[j] = x;
        mx = fmaxf(mx, v[j]);
    }
    for (int o = 32; o; o >>= 1) mx = fmaxf(mx, __shfl_xor(mx, o));
    if ((tid & 63) == 0) red[tid >> 6] = mx;
    __syncthreads();
    mx = fmaxf(fmaxf(red[0], red[1]), fmaxf(red[2], red[3]));
    float s = 0.f;
#pragma unroll
    for (int j = 0; j < 4; j++) {
        int c = tid + j * 256;
        float e = (c < valid) ? __expf(v[j] - mx) : 0.f;
        v[j] = e;
        s += e;
    }
    for (int o = 32; o; o >>= 1) s += __shfl_xor(s, o);
    __syncthreads();
    if ((tid & 63) == 0) red[tid >> 6] = s;
    __syncthreads();
    s = red[0] + red[1] + red[2] + red[3];
    float inv = 1.0f / s;
#pragma unroll
    for (int j = 0; j < 4; j++) {
        int c = tid + j * 256;
        float p = v[j] * inv;
        ushort h = f2bf(p);
        Ph[base + c] = h;
        Pl[base + c] = f2bf(p - bf2f(h));
    }
}

// ---------------- residual + layernorm (f32 in, f32 + h/l planes out) ----------------
__global__ __launch_bounds__(256) void ln_res(const float* __restrict__ xin,
                                              const float* __restrict__ y,
                                              const float* __restrict__ g,
                                              const float* __restrict__ bta,
                                              float* __restrict__ xof,
                                              ushort* __restrict__ xh,
                                              ushort* __restrict__ xl) {
    __shared__ float red[4];
    int row = blockIdx.x;
    size_t base = (size_t)row * D;
    int tid = threadIdx.x;
    int c0 = tid * 4;
    float4 xv = *(const float4*)&xin[base + c0];
    float4 yv = *(const float4*)&y[base + c0];
    float t[4] = {xv.x + yv.x, xv.y + yv.y, xv.z + yv.z, xv.w + yv.w};
    float s = t[0] + t[1] + t[2] + t[3];
    for (int o = 32; o; o >>= 1) s += __shfl_xor(s, o);
    if ((tid & 63) == 0) red[tid >> 6] = s;
    __syncthreads();
    s = red[0] + red[1] + red[2] + red[3];
    float mean = s * (1.0f / D);
    float vs = 0.f;
#pragma unroll
    for (int j = 0; j < 4; j++) {
        float dd = t[j] - mean;
        vs += dd * dd;
    }
    for (int o = 32; o; o >>= 1) vs += __shfl_xor(vs, o);
    __syncthreads();
    if ((tid & 63) == 0) red[tid >> 6] = vs;
    __syncthreads();
    vs = red[0] + red[1] + red[2] + red[3];
    float inv = rsqrtf(vs * (1.0f / D) + 1e-5f);
    float4 gv = *(const float4*)&g[c0];
    float4 bv = *(const float4*)&bta[c0];
    float o0 = (t[0] - mean) * inv * gv.x + bv.x;
    float o1 = (t[1] - mean) * inv * gv.y + bv.y;
    float o2 = (t[2] - mean) * inv * gv.z + bv.z;
    float o3 = (t[3] - mean) * inv * gv.w + bv.w;
    float4 fo = {o0, o1, o2, o3};
    *(float4*)&xof[base + c0] = fo;
    ushort4 h, l;
    h.x = f2bf(o0); l.x = f2bf(o0 - bf2f(h.x));
    h.y = f2bf(o1); l.y = f2bf(o1 - bf2f(h.y));
    h.z = f2bf(o2); l.z = f2bf(o2 - bf2f(h.z));
    h.w = f2bf(o3); l.w = f2bf(o3 - bf2f(h.w));
    *(ushort4*)&xh[base + c0] = h;
    *(ushort4*)&xl[base + c0] = l;
}

__global__ __launch_bounds__(256) void fill_f32(float* out, float v, int n) {
    int i = (blockIdx.x * 256 + threadIdx.x) * 4;
    if (i >= n) return;
    float4 f = {v, v, v, v};
    *(float4*)&out[i] = f;
}

extern "C" void kernel_launch(void* const* d_in, const int* in_sizes, int n_in,
                              void* d_out, int out_size, void* d_ws, size_t ws_size,
                              hipStream_t stream) {
    dim3 blk(256);
    const int M = BATCH * S;  // 4096
    const int fill_blocks = (out_size / 4 + 255) / 256;

    int base = n_in - 18;
    bool layout_ok = (base >= 2) && (out_size == M * D) &&
                     (in_sizes[0] == M * D) && (in_sizes[1] == M * D) &&
                     (in_sizes[base] == L * D * D) && (in_sizes[base + 4] == L * D) &&
                     (in_sizes[base + 12] == L * D * DFF) && (in_sizes[base + 13] == L * DFF);
    if (!layout_ok) {
        fill_f32<<<fill_blocks, blk, 0, stream>>>((float*)d_out, 9000.f, out_size);
        return;
    }
    const float* x_in = (const float*)d_in[0];
    const float* enc  = (const float*)d_in[1];
    const float* Wq1 = (const float*)d_in[base + 0];
    const float* Wk1 = (const float*)d_in[base + 1];
    const float* Wv1 = (const float*)d_in[base + 2];
    const float* Wo1 = (const float*)d_in[base + 3];
    const float* g1  = (const float*)d_in[base + 4];
    const float* b1  = (const float*)d_in[base + 5];
    const float* Wq2 = (const float*)d_in[base + 6];
    const float* Wk2 = (const float*)d_in[base + 7];
    const float* Wv2 = (const float*)d_in[base + 8];
    const float* Wo2 = (const float*)d_in[base + 9];
    const float* g2  = (const float*)d_in[base + 10];
    const float* b2  = (const float*)d_in[base + 11];
    const float* Wf1 = (const float*)d_in[base + 12];
    const float* bf1 = (const float*)d_in[base + 13];
    const float* Wf2 = (const float*)d_in[base + 14];
    const float* bf2 = (const float*)d_in[base + 15];
    const float* g3  = (const float*)d_in[base + 16];
    const float* b3  = (const float*)d_in[base + 17];

    const size_t PL = (size_t)M * D * 2;   // 8 MiB bf16 plane
    const size_t WB = (size_t)D * D * 2;   // 2 MiB weight plane
    const size_t required = 22 * PL;       // 176 MiB
    if (ws_size < required) {
        fill_f32<<<fill_blocks, blk, 0, stream>>>((float*)d_out, 500.f, out_size);
        return;
    }

    char* ws = (char*)d_ws;
    size_t off = 0;
    auto carve = [&](size_t bytes) -> char* {
        char* p = ws + off;
        off += (bytes + 255) & ~(size_t)255;
        return p;
    };
    float*  xf = (float*)carve(2 * PL);
    ushort* xh = (ushort*)carve(PL);     // NOTE: xh,eh adjacent; xl,el adjacent
    ushort* eh = (ushort*)carve(PL);     //   (enables z=2 batched uvo-cross)
    ushort* xl = (ushort*)carve(PL);
    ushort* el = (ushort*)carve(PL);
    char*   clu = carve(10 * PL);        // 80 MiB scratch
    ushort* uvh = (ushort*)clu;                  // u|vo [M][2048] hi (16MB)
    ushort* uvl = (ushort*)(clu + 2 * PL);       // lo (16MB)
    ushort* vth = (ushort*)(clu + 4 * PL);       // vo^T [b][d][s] (8MB)
    ushort* vtl = (ushort*)(clu + 5 * PL);
    float*  scores = (float*)(clu + 6 * PL);     // 16MB
    // weight-prep aliases (scores + spare dead at layer start):
    ushort* Astkh = (ushort*)(clu + 6 * PL);     // [4][D][D] hi (8MB)
    ushort* Astkl = (ushort*)(clu + 7 * PL);
    ushort* Bstkh = (ushort*)(clu + 8 * PL);
    ushort* Bstkl = (ushort*)(clu + 9 * PL);
    // FFN-time aliases:
    float*  wpart = (float*)clu;                 // 32MB partials (u|vo dead)
    ushort* wf2Th = (ushort*)(clu + 4 * PL);     // Wf2^T planes (vt dead)
    ushort* wf2Tl = (ushort*)(clu + 5 * PL);
    ushort* wpH   = (ushort*)(clu + 6 * PL);     // W'^T planes (scores dead)
    ushort* wpL   = (ushort*)(clu + 6 * PL + WB);
    float*  bprime = (float*)(clu + 6 * PL + 2 * WB);
    ushort* ph = (ushort*)carve(PL);
    ushort* pl_ = (ushort*)carve(PL);
    float*  yf = (float*)carve(2 * PL);
    ushort* WTh = (ushort*)carve(PL);    // [4][D][D]: WqkT1, WvoT1, WqkT2, WvoT2
    ushort* WTl = (ushort*)carve(PL);

    auto gemm = [&](const ushort* Ah, const ushort* Al, const ushort* Bh, const ushort* Bl,
                    float* Cf, ushort* Ch, ushort* Cl, const float* bias, float alpha,
                    int gm, int gn, int gk, int lda, int ldb, int ldc,
                    long sA, long sB, long sC, int batch, int tri) {
        dim3 g(gn / 128, gm / 128, batch);
        gemm3<<<g, blk, 0, stream>>>(Ah, Al, Bh, Bl, Cf, Ch, Cl, bias, alpha,
                                     gm, gn, gk, lda, ldb, ldc, sA, sB, sC, tri);
    };
    auto cvtw = [&](const float* W, ushort* oh, ushort* ol) {
        cvt_split<<<(D * D) / 1024, blk, 0, stream>>>(W, oh, ol, D * D);
    };

    cvt_split<<<(M * D) / 1024, blk, 0, stream>>>(x_in, xh, xl, M * D);
    cvt_split<<<(M * D) / 1024, blk, 0, stream>>>(enc, eh, el, M * D);

    const long SM = (long)S * S;
    const long SD = (long)S * D;
    const long DD = (long)D * D;

    for (int i = 0; i < L; i++) {
        size_t wo = (size_t)i * D * D;
        // ===== weight prep: WqkT = Wk@Wq^T ; WvoT = Wo^T@Wv^T (batched z=4) =====
        cvtw(Wk1 + wo, Astkh + 0 * DD, Astkl + 0 * DD);
        transpose_w<<<dim3(D / 32, D / 32), blk, 0, stream>>>(Wo1 + wo, Astkh + 1 * DD, Astkl + 1 * DD, D, D);
        cvtw(Wk2 + wo, Astkh + 2 * DD, Astkl + 2 * DD);
        transpose_w<<<dim3(D / 32, D / 32), blk, 0, stream>>>(Wo2 + wo, Astkh + 3 * DD, Astkl + 3 * DD, D, D);
        cvtw(Wq1 + wo, Bstkh + 0 * DD, Bstkl + 0 * DD);
        cvtw(Wv1 + wo, Bstkh + 1 * DD, Bstkl + 1 * DD);
        cvtw(Wq2 + wo, Bstkh + 2 * DD, Bstkl + 2 * DD);
        cvtw(Wv2 + wo, Bstkh + 3 * DD, Bstkl + 3 * DD);
        gemm(Astkh, Astkl, Bstkh, Bstkl, nullptr, WTh, WTl, nullptr, 1.f,
             D, D, D, D, D, D, DD, DD, DD, 4, 0);

        // ===== self-attention (causal) =====
        // u|vo = x @ [WqkT1; WvoT1]^T  (N=2048)
        gemm(xh, xl, WTh, WTl, nullptr, uvh, uvl, nullptr, 1.f,
             M, 2 * D, D, D, D, 2 * D, 0, 0, 0, 1, 0);
        vtrans<<<dim3(D / 32, S / 32, 2 * BATCH), blk, 0, stream>>>(uvh, uvl, vth, vtl, 2 * D, D);
        gemm(uvh, uvl, xh, xl, scores, nullptr, nullptr, nullptr, 0.125f,
             S, S, D, 2 * D, D, S, (long)S * 2 * D, SD, SM, BATCH, 1);
        softmax_rows<<<dim3(S, BATCH), blk, 0, stream>>>(scores, ph, pl_, 1);
        gemm(ph, pl_, vth, vtl, yf, nullptr, nullptr, nullptr, 1.f,
             S, D, S, S, S, D, SM, SD, SD, BATCH, 2);
        ln_res<<<M, blk, 0, stream>>>((i == 0) ? x_in : xf, yf,
                                      g1 + (size_t)i * D, b1 + (size_t)i * D, xf, xh, xl);

        // ===== cross-attention =====
        // z=0: u = x@WqkT2 ; z=1: vo = enc@WvoT2  (sC=1024 interleaves into [M][2048])
        gemm(xh, xl, WTh + 2 * DD, WTl + 2 * DD, nullptr, uvh, uvl, nullptr, 1.f,
             M, D, D, D, D, 2 * D, (long)M * D, DD, D, 2, 0);
        vtrans<<<dim3(D / 32, S / 32, 2 * BATCH), blk, 0, stream>>>(uvh, uvl, vth, vtl, 2 * D, D);
        gemm(uvh, uvl, eh, el, scores, nullptr, nullptr, nullptr, 0.125f,
             S, S, D, 2 * D, D, S, (long)S * 2 * D, SD, SM, BATCH, 0);
        softmax_rows<<<dim3(S, BATCH), blk, 0, stream>>>(scores, ph, pl_, 0);
        gemm(ph, pl_, vth, vtl, yf, nullptr, nullptr, nullptr, 1.f,
             S, D, S, S, S, D, SM, SD, SD, BATCH, 0);
        ln_res<<<M, blk, 0, stream>>>(xf, yf, g2 + (size_t)i * D, b2 + (size_t)i * D, xf, xh, xl);

        // ===== feedforward (collapsed) =====
        const float* Wf1i = Wf1 + (size_t)i * D * DFF;
        const float* Wf2i = Wf2 + (size_t)i * DFF * D;
        transpose_w<<<dim3(D / 32, DFF / 32), blk, 0, stream>>>(Wf2i, wf2Th, wf2Tl, DFF, D);
        cvt_split<<<(D * DFF) / 1024, blk, 0, stream>>>(Wf1i, ph, pl_, D * DFF);
        gemm(wf2Th, wf2Tl, ph, pl_, wpart, nullptr, nullptr, nullptr, 1.f,
             1024, 1024, 512, DFF, DFF, 1024, 512, 512, 1048576, 8, 0);
        reduce_split<<<1024, blk, 0, stream>>>(wpart, wpH, wpL);
        bias_fold<<<16, blk, 0, stream>>>(bf1 + (size_t)i * DFF, Wf2i,
                                          bf2 + (size_t)i * D, bprime);
        gemm(xh, xl, wpH, wpL, yf, nullptr, nullptr, bprime, 1.f,
             M, D, D, D, D, D, 0, 0, 0, 1, 0);
        ln_res<<<M, blk, 0, stream>>>(xf, yf, g3 + (size_t)i * D, b3 + (size_t)i * D,
                                      (i == L - 1) ? (float*)d_out : xf, xh, xl);
    }
}